// Round 2
// baseline (1404.483 us; speedup 1.0000x reference)
//
#include <hip/hip_runtime.h>
#include <cstdint>
#include <cstdio>
#include <type_traits>

#define DEVINL __device__ __forceinline__

typedef _Float16 f16x8 __attribute__((ext_vector_type(8)));
typedef float    f32x4 __attribute__((ext_vector_type(4)));

static constexpr int B_  = 8;
static constexpr int C_  = 1024;
static constexpr int CI_ = 512;
static constexpr int N_  = 56 * 56;   // 3136
static constexpr int NP  = 3200;      // padded to multiple of 128
static constexpr float BN_EPS = 1e-5f;

DEVINL uint16_t f2h(float f) {
  _Float16 h = (_Float16)f;   // RNE
  union { _Float16 h; uint16_t u; } cv;
  cv.h = h;
  return cv.u;
}

DEVINL void async16(const void* g, void* lds) {
  __builtin_amdgcn_global_load_lds(
      (const __attribute__((address_space(1))) uint32_t*)g,
      (__attribute__((address_space(3))) uint32_t*)lds, 16, 0, 0);
}

// ---------------------------------------------------------------------------
// TN GEMM: C[m,n] = sum_k A[m,k] * Bt[n,k]  (+ optional bias)
// A: [M,K] fp16 row-major, Bt: [N,K] fp16 row-major, C: [M,N] OutT row-major.
// M % 128 == 0, N % 128 == 0, K % 32 == 0. 256 threads, 4 waves in 2x2.
// BIAS: 0 none, 1 per-row (bias[m]), 2 per-col (bias[n]).
// ---------------------------------------------------------------------------
template <typename OutT, int BIAS>
__global__ __launch_bounds__(256) void gemm_tn(
    const uint16_t* __restrict__ A, const uint16_t* __restrict__ Bt,
    OutT* __restrict__ C, const float* __restrict__ bias,
    int M, int N, int K, long aBatch, long bBatch, long cBatch) {
  __shared__ uint16_t As[128 * 32];
  __shared__ uint16_t Bs[128 * 32];

  const int tid = threadIdx.x;
  const int w = tid >> 6, l = tid & 63;
  const int wr = w >> 1, wc = w & 1;
  const int lr = l & 15, lg = l >> 4;

  const long zb = blockIdx.z;
  const uint16_t* Ab = A + zb * aBatch + (long)blockIdx.x * 128 * K;
  const uint16_t* Bb = Bt + zb * bBatch + (long)blockIdx.y * 128 * K;

  // staging: chunk e = r*256 + tid covers 16B; row = e>>2, k-offset = (e&3)*8
  const int r0row = tid >> 2, r0k = (tid & 3) * 8;
  const int r1row = (256 + tid) >> 2, r1k = ((256 + tid) & 3) * 8;
  uint16_t* aD0 = As + (0 * 256 + w * 64) * 8;  // + lane*16B implicit
  uint16_t* aD1 = As + (1 * 256 + w * 64) * 8;
  uint16_t* bD0 = Bs + (0 * 256 + w * 64) * 8;
  uint16_t* bD1 = Bs + (1 * 256 + w * 64) * 8;

  f32x4 acc[4][4] = {};

  for (int k0 = 0; k0 < K; k0 += 32) {
    async16(Ab + (long)r0row * K + k0 + r0k, aD0);
    async16(Ab + (long)r1row * K + k0 + r1k, aD1);
    async16(Bb + (long)r0row * K + k0 + r0k, bD0);
    async16(Bb + (long)r1row * K + k0 + r1k, bD1);
    __syncthreads();

    f16x8 af[4], bfr[4];
#pragma unroll
    for (int i = 0; i < 4; ++i) {
      af[i]  = *reinterpret_cast<const f16x8*>(&As[(wr * 64 + i * 16 + lr) * 32 + lg * 8]);
      bfr[i] = *reinterpret_cast<const f16x8*>(&Bs[(wc * 64 + i * 16 + lr) * 32 + lg * 8]);
    }
#pragma unroll
    for (int i = 0; i < 4; ++i)
#pragma unroll
      for (int j = 0; j < 4; ++j)
        acc[i][j] = __builtin_amdgcn_mfma_f32_16x16x32_f16(af[i], bfr[j], acc[i][j], 0, 0, 0);
    __syncthreads();
  }

  OutT* Cb = C + zb * cBatch + (long)blockIdx.x * 128 * N + (long)blockIdx.y * 128;
#pragma unroll
  for (int i = 0; i < 4; ++i) {
#pragma unroll
    for (int j = 0; j < 4; ++j) {
      const int col = wc * 64 + j * 16 + lr;
      f32x4 v = acc[i][j];
#pragma unroll
      for (int q = 0; q < 4; ++q) {
        const int row = wr * 64 + i * 16 + lg * 4 + q;
        float val = v[q];
        if constexpr (BIAS == 1) val += bias[blockIdx.x * 128 + row];
        if constexpr (BIAS == 2) val += bias[blockIdx.y * 128 + col];
        if constexpr (std::is_same_v<OutT, float>)
          Cb[(long)row * N + col] = val;
        else
          Cb[(long)row * N + col] = f2h(val);
      }
    }
  }
}

// ---------------------------------------------------------------------------
// x [C,N] fp32 -> xT [NP,C] fp16 (zero-padded rows n >= N_)
// ---------------------------------------------------------------------------
__global__ __launch_bounds__(256) void transpose_cast(
    const float* __restrict__ x, uint16_t* __restrict__ xT) {
  __shared__ float t[32][33];
  const int b = blockIdx.z;
  const float* xb = x + (long)b * C_ * N_;
  uint16_t* xTb = xT + (long)b * NP * C_;
  const int n0 = blockIdx.x * 32, c0 = blockIdx.y * 32;
  const int tx = threadIdx.x & 31, ty = threadIdx.x >> 5;
#pragma unroll
  for (int i = 0; i < 4; ++i) {
    const int cc = c0 + ty + i * 8, nn = n0 + tx;
    t[ty + i * 8][tx] = (nn < N_) ? xb[(long)cc * N_ + nn] : 0.f;
  }
  __syncthreads();
#pragma unroll
  for (int i = 0; i < 4; ++i) {
    const int nn = n0 + ty + i * 8, cc = c0 + tx;
    xTb[(long)nn * C_ + cc] = f2h(t[tx][ty + i * 8]);
  }
}

__global__ __launch_bounds__(256) void cvt_f16(
    const float* __restrict__ src, uint16_t* __restrict__ dst, int n) {
  int i = blockIdx.x * 256 + threadIdx.x;
  const int stride = gridDim.x * 256;
  for (; i < n; i += stride) dst[i] = f2h(src[i]);
}

// ---------------------------------------------------------------------------
// row softmax: f [NP,NP] fp32 -> attn [NP,NP] fp16; cols >= N_ zeroed,
// rows >= N_ zeroed entirely.
// ---------------------------------------------------------------------------
__global__ __launch_bounds__(256) void softmax_rows(
    const float* __restrict__ f, uint16_t* __restrict__ attn) {
  const int row = blockIdx.x;
  const int tid = threadIdx.x;
  uint16_t* arow = attn + (long)row * NP;
  if (row >= N_) {
    for (int i = tid; i < NP; i += 256) arow[i] = 0;
    return;
  }
  __shared__ float buf[N_];
  __shared__ float red[8];
  const float* fr = f + (long)row * NP;

  float mx = -3.4e38f;
  for (int i = tid; i < N_; i += 256) {
    const float v = fr[i];
    buf[i] = v;
    mx = fmaxf(mx, v);
  }
  for (int o = 32; o; o >>= 1) mx = fmaxf(mx, __shfl_xor(mx, o));
  if ((tid & 63) == 0) red[tid >> 6] = mx;
  __syncthreads();
  mx = fmaxf(fmaxf(red[0], red[1]), fmaxf(red[2], red[3]));

  float s = 0.f;
  for (int i = tid; i < N_; i += 256) {
    const float e = __expf(buf[i] - mx);
    buf[i] = e;
    s += e;
  }
  for (int o = 32; o; o >>= 1) s += __shfl_xor(s, o);
  __syncthreads();
  if ((tid & 63) == 0) red[tid >> 6] = s;
  __syncthreads();
  const float rinv = 1.0f / (red[0] + red[1] + red[2] + red[3]);

  for (int i = tid; i < N_; i += 256) arow[i] = f2h(buf[i] * rinv);
  for (int i = N_ + tid; i < NP; i += 256) arow[i] = 0;
}

// ---------------------------------------------------------------------------
// BN stats: one block per channel. ss[c] = gamma*rsqrt(var+eps),
// ss[C_+c] = beta - mean*scale.
// ---------------------------------------------------------------------------
__global__ __launch_bounds__(256) void bn_stats(
    const float* __restrict__ z, const float* __restrict__ gamma,
    const float* __restrict__ beta, float* __restrict__ ss) {
  const int c = blockIdx.x, tid = threadIdx.x;
  float sum = 0.f, sq = 0.f;
  for (int b = 0; b < B_; ++b) {
    const float* zp = z + ((long)b * C_ + c) * NP;
    for (int i = tid; i < N_; i += 256) {
      const float v = zp[i];
      sum += v;
      sq += v * v;
    }
  }
  for (int o = 32; o; o >>= 1) {
    sum += __shfl_xor(sum, o);
    sq += __shfl_xor(sq, o);
  }
  __shared__ float r1[8], r2[8];
  if ((tid & 63) == 0) { r1[tid >> 6] = sum; r2[tid >> 6] = sq; }
  __syncthreads();
  if (tid == 0) {
    sum = r1[0] + r1[1] + r1[2] + r1[3];
    sq  = r2[0] + r2[1] + r2[2] + r2[3];
    const float inv_n = 1.0f / (float)(B_ * N_);
    const float mean = sum * inv_n;
    const float var = sq * inv_n - mean * mean;
    const float sc = gamma[c] * rsqrtf(var + BN_EPS);
    ss[c] = sc;
    ss[C_ + c] = beta[c] - mean * sc;
  }
}

__global__ __launch_bounds__(256) void bn_apply(
    const float* __restrict__ z, const float* __restrict__ x,
    const float* __restrict__ ss, float* __restrict__ out) {
  const long nv4 = (long)B_ * C_ * (N_ / 4);
  const long stride = (long)gridDim.x * 256;
  for (long v = (long)blockIdx.x * 256 + threadIdx.x; v < nv4; v += stride) {
    const long rowidx = v / (N_ / 4);
    const int n4 = (int)(v % (N_ / 4));
    const int c = (int)(rowidx % C_);
    const float4 zz = *(const float4*)(z + rowidx * NP + (long)n4 * 4);
    const float4 xx = *(const float4*)(x + rowidx * (long)N_ + (long)n4 * 4);
    const float sc = ss[c], sh = ss[C_ + c];
    float4 o;
    o.x = zz.x * sc + sh + xx.x;
    o.y = zz.y * sc + sh + xx.y;
    o.z = zz.z * sc + sh + xx.z;
    o.w = zz.w * sc + sh + xx.w;
    *(float4*)(out + rowidx * (long)N_ + (long)n4 * 4) = o;
  }
}

// ---------------------------------------------------------------------------
extern "C" void kernel_launch(void* const* d_in, const int* in_sizes, int n_in,
                              void* d_out, int out_size, void* d_ws,
                              size_t ws_size, hipStream_t stream) {
  const float* x       = (const float*)d_in[0];
  const float* theta_w = (const float*)d_in[1];
  const float* theta_b = (const float*)d_in[2];
  const float* phi_w   = (const float*)d_in[3];
  const float* phi_b   = (const float*)d_in[4];
  const float* g_w     = (const float*)d_in[5];
  const float* g_b     = (const float*)d_in[6];
  const float* wz_w    = (const float*)d_in[7];
  const float* wz_b    = (const float*)d_in[8];
  const float* gamma   = (const float*)d_in[9];
  const float* beta    = (const float*)d_in[10];
  float* out = (float*)d_out;

  char* ws = (char*)d_ws;
  size_t off = 0;
  auto alloc = [&](size_t bytes) {
    void* p = ws + off;
    off += (bytes + 255) & ~(size_t)255;
    return p;
  };
  uint16_t* xT     = (uint16_t*)alloc((size_t)B_ * NP * C_ * 2);
  uint16_t* wth    = (uint16_t*)alloc((size_t)CI_ * C_ * 2);
  uint16_t* wph    = (uint16_t*)alloc((size_t)CI_ * C_ * 2);
  uint16_t* wg     = (uint16_t*)alloc((size_t)CI_ * C_ * 2);
  uint16_t* wz     = (uint16_t*)alloc((size_t)C_ * CI_ * 2);
  uint16_t* thetaT = (uint16_t*)alloc((size_t)B_ * NP * CI_ * 2);
  uint16_t* phiT   = (uint16_t*)alloc((size_t)B_ * NP * CI_ * 2);
  uint16_t* gbuf   = (uint16_t*)alloc((size_t)B_ * CI_ * NP * 2);
  uint16_t* ybuf   = (uint16_t*)alloc((size_t)B_ * NP * CI_ * 2);
  float*    zbuf   = (float*)alloc((size_t)B_ * C_ * NP * 4);
  float*    fbuf   = (float*)alloc((size_t)NP * NP * 4);
  uint16_t* attn   = (uint16_t*)alloc((size_t)NP * NP * 2);
  float*    ss     = (float*)alloc((size_t)C_ * 2 * 4);
  if (off > ws_size) {
    fprintf(stderr, "kernel_launch: workspace too small: need %zu have %zu\n",
            off, ws_size);
    return;
  }

  // weight conversion
  cvt_f16<<<512, 256, 0, stream>>>(theta_w, wth, CI_ * C_);
  cvt_f16<<<512, 256, 0, stream>>>(phi_w, wph, CI_ * C_);
  cvt_f16<<<512, 256, 0, stream>>>(g_w, wg, CI_ * C_);
  cvt_f16<<<512, 256, 0, stream>>>(wz_w, wz, C_ * CI_);

  // x -> xT fp16 [B, NP, C]
  transpose_cast<<<dim3(NP / 32, C_ / 32, B_), 256, 0, stream>>>(x, xT);

  // thetaT[bn,ci] and phiT[bn,ci]: A = xT [B*NP, C], Bt = W [CI, C]
  gemm_tn<uint16_t, 2><<<dim3(B_ * NP / 128, CI_ / 128, 1), 256, 0, stream>>>(
      xT, wth, thetaT, theta_b, B_ * NP, CI_, C_, 0, 0, 0);
  gemm_tn<uint16_t, 2><<<dim3(B_ * NP / 128, CI_ / 128, 1), 256, 0, stream>>>(
      xT, wph, phiT, phi_b, B_ * NP, CI_, C_, 0, 0, 0);
  // g[ci,n] per batch: A = W_g [CI, C], Bt = xT_b [NP, C]
  gemm_tn<uint16_t, 1><<<dim3(CI_ / 128, NP / 128, B_), 256, 0, stream>>>(
      wg, xT, gbuf, g_b, CI_, NP, C_, 0, (long)NP * C_, (long)CI_ * NP);

  for (int b = 0; b < B_; ++b) {
    const uint16_t* thb = thetaT + (size_t)b * NP * CI_;
    const uint16_t* phb = phiT + (size_t)b * NP * CI_;
    const uint16_t* gb  = gbuf + (size_t)b * CI_ * NP;
    uint16_t* yb = ybuf + (size_t)b * NP * CI_;
    float* zb = zbuf + (size_t)b * C_ * NP;
    // f = thetaT @ phiT^T : [NP, NP] fp32
    gemm_tn<float, 0><<<dim3(NP / 128, NP / 128, 1), 256, 0, stream>>>(
        thb, phb, fbuf, nullptr, NP, NP, CI_, 0, 0, 0);
    softmax_rows<<<NP, 256, 0, stream>>>(fbuf, attn);
    // y = attn @ g^T : [NP, CI] fp16
    gemm_tn<uint16_t, 0><<<dim3(NP / 128, CI_ / 128, 1), 256, 0, stream>>>(
        attn, gb, yb, nullptr, NP, CI_, NP, 0, 0, 0);
    // z = wz @ y^T : [C, NP] fp32 (+bias per row)
    gemm_tn<float, 1><<<dim3(C_ / 128, NP / 128, 1), 256, 0, stream>>>(
        wz, yb, zb, wz_b, C_, NP, CI_, 0, 0, 0);
  }

  bn_stats<<<C_, 256, 0, stream>>>(zbuf, gamma, beta, ss);
  bn_apply<<<4096, 256, 0, stream>>>(zbuf, x, ss, out);
}

// Round 3
// 902.787 us; speedup vs baseline: 1.5557x; 1.5557x over previous
//
#include <hip/hip_runtime.h>
#include <cstdint>
#include <cstdio>
#include <type_traits>

#define DEVINL __device__ __forceinline__

typedef _Float16 f16x8 __attribute__((ext_vector_type(8)));
typedef float    f32x4 __attribute__((ext_vector_type(4)));

static constexpr int B_  = 8;
static constexpr int C_  = 1024;
static constexpr int CI_ = 512;
static constexpr int N_  = 56 * 56;   // 3136
static constexpr int NP  = 3200;      // padded to multiple of 128
static constexpr float BN_EPS = 1e-5f;

DEVINL uint16_t f2h(float f) {
  union { _Float16 h; uint16_t u; } cv;
  cv.h = (_Float16)f;   // RNE
  return cv.u;
}

DEVINL void async16(const void* g, void* lds) {
  __builtin_amdgcn_global_load_lds(
      (const __attribute__((address_space(1))) uint32_t*)g,
      (__attribute__((address_space(3))) uint32_t*)lds, 16, 0, 0);
}

// ---------------------------------------------------------------------------
// TN GEMM, 2-phase double-buffered (T3-minimum recipe):
// C[m,n] = sum_k A[m,k] * Bt[n,k]  (+ optional bias)
// A: [M,K] fp16 row-major, Bt: [N,K] fp16 row-major, C: [M,N] OutT row-major.
// M % 128 == 0, N % 128 == 0, K % 32 == 0. 256 threads, 4 waves in 2x2.
// BIAS: 0 none, 1 per-row (bias[m]), 2 per-col (bias[n]).
// ---------------------------------------------------------------------------
template <typename OutT, int BIAS>
__global__ __launch_bounds__(256) void gemm_tn(
    const uint16_t* __restrict__ A, const uint16_t* __restrict__ Bt,
    OutT* __restrict__ C, const float* __restrict__ bias,
    int M, int N, int K, long aBatch, long bBatch, long cBatch) {
  __shared__ uint16_t As[2][128 * 32];
  __shared__ uint16_t Bs[2][128 * 32];

  const int tid = threadIdx.x;
  const int w = tid >> 6, l = tid & 63;
  const int wr = w >> 1, wc = w & 1;
  const int lr = l & 15, lg = l >> 4;

  const long zb = blockIdx.z;
  const uint16_t* Ab = A + zb * aBatch + (long)blockIdx.x * 128 * K;
  const uint16_t* Bb = Bt + zb * bBatch + (long)blockIdx.y * 128 * K;

  // staging: chunk e = r*256 + tid covers 16B; row = e>>2, k-offset = (e&3)*8
  const int r0row = tid >> 2, r0k = (tid & 3) * 8;
  const int r1row = (256 + tid) >> 2, r1k = ((256 + tid) & 3) * 8;
  const int d0 = (w * 64) * 8;         // wave-uniform LDS chunk base (elements)
  const int d1 = (256 + w * 64) * 8;

  auto stage = [&](int buf, int k0) {
    async16(Ab + (long)r0row * K + k0 + r0k, &As[buf][d0]);
    async16(Ab + (long)r1row * K + k0 + r1k, &As[buf][d1]);
    async16(Bb + (long)r0row * K + k0 + r0k, &Bs[buf][d0]);
    async16(Bb + (long)r1row * K + k0 + r1k, &Bs[buf][d1]);
  };

  f32x4 acc[4][4] = {};
  const int nk = K >> 5;

  stage(0, 0);
  asm volatile("s_waitcnt vmcnt(0)" ::: "memory");
  __builtin_amdgcn_s_barrier();

  int cur = 0;
  for (int t = 0; t < nk; ++t) {
    if (t + 1 < nk) stage(cur ^ 1, (t + 1) * 32);  // prefetch next tile

    f16x8 af[4], bfr[4];
#pragma unroll
    for (int i = 0; i < 4; ++i) {
      af[i]  = *reinterpret_cast<const f16x8*>(&As[cur][(wr * 64 + i * 16 + lr) * 32 + lg * 8]);
      bfr[i] = *reinterpret_cast<const f16x8*>(&Bs[cur][(wc * 64 + i * 16 + lr) * 32 + lg * 8]);
    }
#pragma unroll
    for (int i = 0; i < 4; ++i)
#pragma unroll
      for (int j = 0; j < 4; ++j)
        acc[i][j] = __builtin_amdgcn_mfma_f32_16x16x32_f16(af[i], bfr[j], acc[i][j], 0, 0, 0);

    asm volatile("s_waitcnt vmcnt(0)" ::: "memory");  // next tile landed
    __builtin_amdgcn_s_barrier();
    cur ^= 1;
  }

  OutT* Cb = C + zb * cBatch + (long)blockIdx.x * 128 * N + (long)blockIdx.y * 128;
#pragma unroll
  for (int i = 0; i < 4; ++i) {
#pragma unroll
    for (int j = 0; j < 4; ++j) {
      const int col = wc * 64 + j * 16 + lr;
      f32x4 v = acc[i][j];
#pragma unroll
      for (int q = 0; q < 4; ++q) {
        const int row = wr * 64 + i * 16 + lg * 4 + q;
        float val = v[q];
        if constexpr (BIAS == 1) val += bias[blockIdx.x * 128 + row];
        if constexpr (BIAS == 2) val += bias[blockIdx.y * 128 + col];
        if constexpr (std::is_same_v<OutT, float>)
          Cb[(long)row * N + col] = val;
        else
          Cb[(long)row * N + col] = f2h(val);
      }
    }
  }
}

// ---------------------------------------------------------------------------
// x [C,N] fp32 -> xT [NP,C] fp16 (zero-padded rows n >= N_)
// ---------------------------------------------------------------------------
__global__ __launch_bounds__(256) void transpose_cast(
    const float* __restrict__ x, uint16_t* __restrict__ xT) {
  __shared__ float t[32][33];
  const int b = blockIdx.z;
  const float* xb = x + (long)b * C_ * N_;
  uint16_t* xTb = xT + (long)b * NP * C_;
  const int n0 = blockIdx.x * 32, c0 = blockIdx.y * 32;
  const int tx = threadIdx.x & 31, ty = threadIdx.x >> 5;
#pragma unroll
  for (int i = 0; i < 4; ++i) {
    const int cc = c0 + ty + i * 8, nn = n0 + tx;
    t[ty + i * 8][tx] = (nn < N_) ? xb[(long)cc * N_ + nn] : 0.f;
  }
  __syncthreads();
#pragma unroll
  for (int i = 0; i < 4; ++i) {
    const int nn = n0 + ty + i * 8, cc = c0 + tx;
    xTb[(long)nn * C_ + cc] = f2h(t[tx][ty + i * 8]);
  }
}

__global__ __launch_bounds__(256) void cvt_f16(
    const float* __restrict__ src, uint16_t* __restrict__ dst, int n) {
  int i = blockIdx.x * 256 + threadIdx.x;
  const int stride = gridDim.x * 256;
  for (; i < n; i += stride) dst[i] = f2h(src[i]);
}

// ---------------------------------------------------------------------------
// row softmax: f [NP,NP] fp32 -> attn [NP,NP] fp16; cols >= N_ zeroed,
// rows >= N_ zeroed. blockIdx.x = row, blockIdx.y = batch-in-group.
// ---------------------------------------------------------------------------
__global__ __launch_bounds__(256) void softmax_rows(
    const float* __restrict__ f, uint16_t* __restrict__ attn) {
  const int row = blockIdx.x;
  const long by = blockIdx.y;
  const int tid = threadIdx.x;
  uint16_t* arow = attn + by * NP * NP + (long)row * NP;
  if (row >= N_) {
    for (int i = tid; i < NP; i += 256) arow[i] = 0;
    return;
  }
  __shared__ float buf[N_];
  __shared__ float red[8];
  const float* fr = f + by * NP * NP + (long)row * NP;

  float mx = -3.4e38f;
  for (int i = tid; i < N_; i += 256) {
    const float v = fr[i];
    buf[i] = v;
    mx = fmaxf(mx, v);
  }
  for (int o = 32; o; o >>= 1) mx = fmaxf(mx, __shfl_xor(mx, o));
  if ((tid & 63) == 0) red[tid >> 6] = mx;
  __syncthreads();
  mx = fmaxf(fmaxf(red[0], red[1]), fmaxf(red[2], red[3]));

  float s = 0.f;
  for (int i = tid; i < N_; i += 256) {
    const float e = __expf(buf[i] - mx);
    buf[i] = e;
    s += e;
  }
  for (int o = 32; o; o >>= 1) s += __shfl_xor(s, o);
  __syncthreads();
  if ((tid & 63) == 0) red[tid >> 6] = s;
  __syncthreads();
  const float rinv = 1.0f / (red[0] + red[1] + red[2] + red[3]);

  for (int i = tid; i < N_; i += 256) arow[i] = f2h(buf[i] * rinv);
  for (int i = N_ + tid; i < NP; i += 256) arow[i] = 0;
}

// ---------------------------------------------------------------------------
// BN stats over fp16 z. ss[c] = gamma*rsqrt(var+eps), ss[C_+c] = beta - mean*sc
// ---------------------------------------------------------------------------
__global__ __launch_bounds__(256) void bn_stats(
    const _Float16* __restrict__ z, const float* __restrict__ gamma,
    const float* __restrict__ beta, float* __restrict__ ss) {
  const int c = blockIdx.x, tid = threadIdx.x;
  float sum = 0.f, sq = 0.f;
  for (int b = 0; b < B_; ++b) {
    const _Float16* zp = z + ((long)b * C_ + c) * NP;
    for (int ch = tid; ch < N_ / 8; ch += 256) {
      const f16x8 v = *(const f16x8*)(zp + ch * 8);
#pragma unroll
      for (int j = 0; j < 8; ++j) {
        const float fv = (float)v[j];
        sum += fv;
        sq += fv * fv;
      }
    }
  }
  for (int o = 32; o; o >>= 1) {
    sum += __shfl_xor(sum, o);
    sq += __shfl_xor(sq, o);
  }
  __shared__ float r1[8], r2[8];
  if ((tid & 63) == 0) { r1[tid >> 6] = sum; r2[tid >> 6] = sq; }
  __syncthreads();
  if (tid == 0) {
    sum = r1[0] + r1[1] + r1[2] + r1[3];
    sq  = r2[0] + r2[1] + r2[2] + r2[3];
    const float inv_n = 1.0f / (float)(B_ * N_);
    const float mean = sum * inv_n;
    const float var = sq * inv_n - mean * mean;
    const float sc = gamma[c] * rsqrtf(var + BN_EPS);
    ss[c] = sc;
    ss[C_ + c] = beta[c] - mean * sc;
  }
}

__global__ __launch_bounds__(256) void bn_apply(
    const _Float16* __restrict__ z, const float* __restrict__ x,
    const float* __restrict__ ss, float* __restrict__ out) {
  constexpr int CH = N_ / 8;  // 392 8-element chunks per row
  const long nv = (long)B_ * C_ * CH;
  const long stride = (long)gridDim.x * 256;
  for (long v = (long)blockIdx.x * 256 + threadIdx.x; v < nv; v += stride) {
    const long row = v / CH;
    const int ch = (int)(v % CH);
    const int c = (int)(row % C_);
    const f16x8 zz = *(const f16x8*)(z + row * NP + ch * 8);
    const float4 x0 = *(const float4*)(x + row * (long)N_ + ch * 8);
    const float4 x1 = *(const float4*)(x + row * (long)N_ + ch * 8 + 4);
    const float sc = ss[c], sh = ss[C_ + c];
    float4 o0, o1;
    o0.x = (float)zz[0] * sc + sh + x0.x;
    o0.y = (float)zz[1] * sc + sh + x0.y;
    o0.z = (float)zz[2] * sc + sh + x0.z;
    o0.w = (float)zz[3] * sc + sh + x0.w;
    o1.x = (float)zz[4] * sc + sh + x1.x;
    o1.y = (float)zz[5] * sc + sh + x1.y;
    o1.z = (float)zz[6] * sc + sh + x1.z;
    o1.w = (float)zz[7] * sc + sh + x1.w;
    *(float4*)(out + row * (long)N_ + ch * 8) = o0;
    *(float4*)(out + row * (long)N_ + ch * 8 + 4) = o1;
  }
}

// ---------------------------------------------------------------------------
extern "C" void kernel_launch(void* const* d_in, const int* in_sizes, int n_in,
                              void* d_out, int out_size, void* d_ws,
                              size_t ws_size, hipStream_t stream) {
  const float* x       = (const float*)d_in[0];
  const float* theta_w = (const float*)d_in[1];
  const float* theta_b = (const float*)d_in[2];
  const float* phi_w   = (const float*)d_in[3];
  const float* phi_b   = (const float*)d_in[4];
  const float* g_w     = (const float*)d_in[5];
  const float* g_b     = (const float*)d_in[6];
  const float* wz_w    = (const float*)d_in[7];
  const float* wz_b    = (const float*)d_in[8];
  const float* gamma   = (const float*)d_in[9];
  const float* beta    = (const float*)d_in[10];
  float* out = (float*)d_out;

  char* ws = (char*)d_ws;
  size_t off = 0;
  auto alloc = [&](size_t bytes) {
    void* p = ws + off;
    off += (bytes + 255) & ~(size_t)255;
    return p;
  };
  uint16_t* xT     = (uint16_t*)alloc((size_t)B_ * NP * C_ * 2);
  uint16_t* wth    = (uint16_t*)alloc((size_t)CI_ * C_ * 2);
  uint16_t* wph    = (uint16_t*)alloc((size_t)CI_ * C_ * 2);
  uint16_t* wg     = (uint16_t*)alloc((size_t)CI_ * C_ * 2);
  uint16_t* wz     = (uint16_t*)alloc((size_t)C_ * CI_ * 2);
  uint16_t* thetaT = (uint16_t*)alloc((size_t)B_ * NP * CI_ * 2);
  uint16_t* phiT   = (uint16_t*)alloc((size_t)B_ * NP * CI_ * 2);
  uint16_t* gbuf   = (uint16_t*)alloc((size_t)B_ * CI_ * NP * 2);
  uint16_t* ybuf   = (uint16_t*)alloc((size_t)B_ * NP * CI_ * 2);
  uint16_t* zbuf   = (uint16_t*)alloc((size_t)B_ * C_ * NP * 2);
  float*    ss     = (float*)alloc((size_t)C_ * 2 * 4);

  // adaptive attention batching group: largest G in {8,4,2,1} that fits
  const size_t perG = (size_t)NP * NP * 4 + (size_t)NP * NP * 2 + 512;
  int G = 8;
  while (G > 1 && off + (size_t)G * perG > ws_size) G >>= 1;
  float*    fbuf = (float*)alloc((size_t)G * NP * NP * 4);
  uint16_t* attn = (uint16_t*)alloc((size_t)G * NP * NP * 2);
  if (off > ws_size) {
    fprintf(stderr, "kernel_launch: workspace too small: need %zu have %zu\n",
            off, ws_size);
    return;
  }

  // weight conversion
  cvt_f16<<<512, 256, 0, stream>>>(theta_w, wth, CI_ * C_);
  cvt_f16<<<512, 256, 0, stream>>>(phi_w, wph, CI_ * C_);
  cvt_f16<<<512, 256, 0, stream>>>(g_w, wg, CI_ * C_);
  cvt_f16<<<512, 256, 0, stream>>>(wz_w, wz, C_ * CI_);

  // x -> xT fp16 [B, NP, C]
  transpose_cast<<<dim3(NP / 32, C_ / 32, B_), 256, 0, stream>>>(x, xT);

  // thetaT[bn,ci] and phiT[bn,ci]: A = xT [B*NP, C], Bt = W [CI, C]
  gemm_tn<uint16_t, 2><<<dim3(B_ * NP / 128, CI_ / 128, 1), 256, 0, stream>>>(
      xT, wth, thetaT, theta_b, B_ * NP, CI_, C_, 0, 0, 0);
  gemm_tn<uint16_t, 2><<<dim3(B_ * NP / 128, CI_ / 128, 1), 256, 0, stream>>>(
      xT, wph, phiT, phi_b, B_ * NP, CI_, C_, 0, 0, 0);
  // g[ci,n] per batch: A = W_g [CI, C], Bt = xT_b [NP, C]
  gemm_tn<uint16_t, 1><<<dim3(CI_ / 128, NP / 128, B_), 256, 0, stream>>>(
      wg, xT, gbuf, g_b, CI_, NP, C_, 0, (long)NP * C_, (long)CI_ * NP);

  for (int g0 = 0; g0 < B_; g0 += G) {
    const uint16_t* thb = thetaT + (size_t)g0 * NP * CI_;
    const uint16_t* phb = phiT + (size_t)g0 * NP * CI_;
    const uint16_t* gb  = gbuf + (size_t)g0 * CI_ * NP;
    uint16_t* yb = ybuf + (size_t)g0 * NP * CI_;
    uint16_t* zb = zbuf + (size_t)g0 * C_ * NP;
    // f = thetaT @ phiT^T : [NP, NP] fp32, batched over G
    gemm_tn<float, 0><<<dim3(NP / 128, NP / 128, G), 256, 0, stream>>>(
        thb, phb, fbuf, nullptr, NP, NP, CI_,
        (long)NP * CI_, (long)NP * CI_, (long)NP * NP);
    softmax_rows<<<dim3(NP, G, 1), 256, 0, stream>>>(fbuf, attn);
    // y = attn @ g^T : [NP, CI] fp16, batched over G
    gemm_tn<uint16_t, 0><<<dim3(NP / 128, CI_ / 128, G), 256, 0, stream>>>(
        attn, gb, yb, nullptr, NP, CI_, NP,
        (long)NP * NP, (long)CI_ * NP, (long)NP * CI_);
    // z = wz @ y^T : [C, NP] fp16 (+bias per row), batched over G
    gemm_tn<uint16_t, 1><<<dim3(C_ / 128, NP / 128, G), 256, 0, stream>>>(
        wz, yb, zb, wz_b, C_, NP, CI_,
        0, (long)NP * CI_, (long)C_ * NP);
  }

  bn_stats<<<C_, 256, 0, stream>>>((const _Float16*)zbuf, gamma, beta, ss);
  bn_apply<<<4096, 256, 0, stream>>>((const _Float16*)zbuf, x, ss, out);
}

// Round 4
// 530.482 us; speedup vs baseline: 2.6476x; 1.7018x over previous
//
#include <hip/hip_runtime.h>
#include <cstdint>
#include <cstdio>

#define DEVINL __device__ __forceinline__

typedef _Float16 f16x8 __attribute__((ext_vector_type(8)));
typedef float    f32x4 __attribute__((ext_vector_type(4)));

static constexpr int B_  = 8;
static constexpr int C_  = 1024;
static constexpr int CI_ = 512;
static constexpr int N_  = 56 * 56;   // 3136
static constexpr int NP  = 3328;      // padded to multiple of 256
static constexpr float BN_EPS = 1e-5f;

DEVINL uint16_t f2h(float f) {
  union { _Float16 h; uint16_t u; } cv;
  cv.h = (_Float16)f;   // RNE
  return cv.u;
}

DEVINL void async16(const void* g, void* lds) {
  __builtin_amdgcn_global_load_lds(
      (const __attribute__((address_space(1))) uint32_t*)g,
      (__attribute__((address_space(3))) uint32_t*)lds, 16, 0, 0);
}

// ---------------------------------------------------------------------------
// 256x256 8-phase TN GEMM (m201 template, fp16 in / fp16 out, fp32 acc).
// C[m,n] = sum_k A[m,k]*Bt[n,k] (+bias). M%256==0, N%256==0, K%128==0.
// 512 threads = 8 waves (2M x 4N); per-wave output 128x64; acc[8][4] f32x4.
// LDS 128KB: A/B x 2 bufs x 2 k-slices(32) of [256][32] fp16 (16KB half-tiles).
// Swizzle: chunk16B c within row: phys = c ^ (row&3)  (both sides: staged
// source pre-swizzled, ds_read applies same XOR).  Counted vmcnt(8) only,
// twice per K-tile; per-phase barrier + lgkmcnt(0) + sched_barrier(0).
// BIAS: 0 none, 1 per-row, 2 per-col.
// ---------------------------------------------------------------------------
template <int BIAS>
__global__ __launch_bounds__(512, 2) void gemm256(
    const uint16_t* __restrict__ A, const uint16_t* __restrict__ Bt,
    uint16_t* __restrict__ Cc, const float* __restrict__ bias,
    int K, int lda, int ldb, int ldc,
    long aBatch, long bBatch, long cBatch, int nbx, int nby) {
  __shared__ uint16_t lds[65536];   // 128 KiB

  // bijective XCD swizzle (m204)
  const int nwg = gridDim.x, orig = blockIdx.x;
  const int q = nwg >> 3, r = nwg & 7, xcd = orig & 7, idx = orig >> 3;
  const int wgid = (xcd < r ? xcd * (q + 1) : r * (q + 1) + (xcd - r) * q) + idx;
  const int bx = wgid % nbx;
  const int by = (wgid / nbx) % nby;
  const int zb = wgid / (nbx * nby);

  const int tid = threadIdx.x, w = tid >> 6, l = tid & 63;
  const int wm = w >> 2, wn = w & 3, lr = l & 15, lg = l >> 4;

  const uint16_t* Ab = A + (long)zb * aBatch + (long)bx * 256 * lda;
  const uint16_t* Bb = Bt + (long)zb * bBatch + (long)by * 256 * ldb;

  const int NT = K >> 6;

  // staging: half-tile = [256 rows][32 k] fp16 = 1024 chunks of 16B, 2 instrs.
  // chunk c: row=c>>2, source col pre-swizzled: ((c&3)^(row&3))*8
  const int c0 = tid, c1 = 512 + tid;
  const long aoff0 = (long)(c0 >> 2) * lda + (((c0 & 3) ^ ((c0 >> 2) & 3)) * 8);
  const long aoff1 = (long)(c1 >> 2) * lda + (((c1 & 3) ^ ((c1 >> 2) & 3)) * 8);
  const long boff0 = (long)(c0 >> 2) * ldb + (((c0 & 3) ^ ((c0 >> 2) & 3)) * 8);
  const long boff1 = (long)(c1 >> 2) * ldb + (((c1 & 3) ^ ((c1 >> 2) & 3)) * 8);
  const int ldsW0 = (w * 64) * 8;          // wave-uniform dest (elems), instr 0
  const int ldsW1 = (512 + w * 64) * 8;    // instr 1

  auto stageA = [&](int t, int ks, int buf) {
    const int tw = t >= NT ? t - NT : t;   // wrap: garbage lands in dead region
    const uint16_t* src = Ab + tw * 64 + ks * 32;
    const int reg = (buf * 2 + ks) * 8192;
    async16(src + aoff0, &lds[reg + ldsW0]);
    async16(src + aoff1, &lds[reg + ldsW1]);
  };
  auto stageB = [&](int t, int ks, int buf) {
    const int tw = t >= NT ? t - NT : t;
    const uint16_t* src = Bb + tw * 64 + ks * 32;
    const int reg = 32768 + (buf * 2 + ks) * 8192;
    async16(src + boff0, &lds[reg + ldsW0]);
    async16(src + boff1, &lds[reg + ldsW1]);
  };

  const int laneSwz = (lg ^ (lr & 3)) * 8;  // swizzled 16B-chunk within row
  f32x4 acc[8][4] = {};
  f16x8 af[4], bf[4];

#define LOAD_A(b, ks, mh)                                                     \
  _Pragma("unroll") for (int i = 0; i < 4; ++i) {                             \
    const int row_ = wm * 128 + ((mh) * 4 + i) * 16 + lr;                     \
    af[i] = *reinterpret_cast<const f16x8*>(                                  \
        &lds[((b) * 2 + (ks)) * 8192 + row_ * 32 + laneSwz]);                 \
  }
#define LOAD_B(b, ks)                                                         \
  _Pragma("unroll") for (int i = 0; i < 4; ++i) {                             \
    const int row_ = wn * 64 + i * 16 + lr;                                   \
    bf[i] = *reinterpret_cast<const f16x8*>(                                  \
        &lds[32768 + ((b) * 2 + (ks)) * 8192 + row_ * 32 + laneSwz]);         \
  }
#define MFMA16(mh)                                                            \
  _Pragma("unroll") for (int i = 0; i < 4; ++i)                               \
  _Pragma("unroll") for (int j = 0; j < 4; ++j)                               \
    acc[(mh) * 4 + i][j] = __builtin_amdgcn_mfma_f32_16x16x32_f16(            \
        af[i], bf[j], acc[(mh) * 4 + i][j], 0, 0, 0);
#define WAIT_LGKM()                                       \
  asm volatile("s_waitcnt lgkmcnt(0)" ::: "memory");      \
  __builtin_amdgcn_sched_barrier(0);
#define WAIT_VM8()                                        \
  asm volatile("s_waitcnt vmcnt(8)" ::: "memory");        \
  __builtin_amdgcn_sched_barrier(0);

#define TILE(t, b)                                                            \
  {                                                                           \
    /* P1: k-slice0, m-half0 */                                               \
    LOAD_B(b, 0); LOAD_A(b, 0, 0);                                            \
    stageA((t) + 1, 1, (b) ^ 1);                                              \
    __builtin_amdgcn_s_barrier(); WAIT_LGKM();                                \
    __builtin_amdgcn_s_setprio(1); MFMA16(0); __builtin_amdgcn_s_setprio(0);  \
    __builtin_amdgcn_s_barrier();                                             \
    /* P2: k-slice0, m-half1 */                                               \
    LOAD_A(b, 0, 1);                                                          \
    stageB((t) + 1, 1, (b) ^ 1);                                              \
    __builtin_amdgcn_s_barrier(); WAIT_LGKM();                                \
    __builtin_amdgcn_s_setprio(1); MFMA16(1); __builtin_amdgcn_s_setprio(0);  \
    WAIT_VM8();                                                               \
    __builtin_amdgcn_s_barrier();                                             \
    /* P3: k-slice1, m-half0 */                                               \
    LOAD_B(b, 1); LOAD_A(b, 1, 0);                                            \
    stageA((t) + 2, 0, (b));                                                  \
    __builtin_amdgcn_s_barrier(); WAIT_LGKM();                                \
    __builtin_amdgcn_s_setprio(1); MFMA16(0); __builtin_amdgcn_s_setprio(0);  \
    __builtin_amdgcn_s_barrier();                                             \
    /* P4: k-slice1, m-half1 */                                               \
    LOAD_A(b, 1, 1);                                                          \
    stageB((t) + 2, 0, (b));                                                  \
    __builtin_amdgcn_s_barrier(); WAIT_LGKM();                                \
    __builtin_amdgcn_s_setprio(1); MFMA16(1); __builtin_amdgcn_s_setprio(0);  \
    WAIT_VM8();                                                               \
    __builtin_amdgcn_s_barrier();                                             \
  }

  // prologue: tile0 (all 4 halves) + tile1 k-slice0 = 6 stages (12 loads);
  // vmcnt(8) -> oldest 4 loads (A/B k0 of tile0) landed.
  stageA(0, 0, 0); stageB(0, 0, 0);
  stageA(0, 1, 0); stageB(0, 1, 0);
  stageA(1, 0, 1); stageB(1, 0, 1);
  WAIT_VM8();
  __builtin_amdgcn_s_barrier();

  for (int tp = 0; tp < NT; tp += 2) {   // K%128==0 -> NT even
    TILE(tp, 0);
    TILE(tp + 1, 1);
  }

#undef TILE
#undef LOAD_A
#undef LOAD_B
#undef MFMA16
#undef WAIT_LGKM
#undef WAIT_VM8

  uint16_t* Cp = Cc + (long)zb * cBatch + ((long)bx * 256) * ldc + (long)by * 256;
#pragma unroll
  for (int mf = 0; mf < 8; ++mf) {
#pragma unroll
    for (int nf = 0; nf < 4; ++nf) {
      const int col = wn * 64 + nf * 16 + lr;
      const f32x4 v = acc[mf][nf];
#pragma unroll
      for (int qq = 0; qq < 4; ++qq) {
        const int row = wm * 128 + mf * 16 + lg * 4 + qq;
        float val = v[qq];
        if constexpr (BIAS == 1) val += bias[bx * 256 + row];
        if constexpr (BIAS == 2) val += bias[by * 256 + col];
        Cp[(long)row * ldc + col] = f2h(val);
      }
    }
  }
}

// ---------------------------------------------------------------------------
// x [C,N] fp32 -> xT [NP,C] fp16 (zero-padded rows n >= N_)
// ---------------------------------------------------------------------------
__global__ __launch_bounds__(256) void transpose_cast(
    const float* __restrict__ x, uint16_t* __restrict__ xT) {
  __shared__ float t[32][33];
  const int b = blockIdx.z;
  const float* xb = x + (long)b * C_ * N_;
  uint16_t* xTb = xT + (long)b * NP * C_;
  const int n0 = blockIdx.x * 32, c0 = blockIdx.y * 32;
  const int tx = threadIdx.x & 31, ty = threadIdx.x >> 5;
#pragma unroll
  for (int i = 0; i < 4; ++i) {
    const int cc = c0 + ty + i * 8, nn = n0 + tx;
    t[ty + i * 8][tx] = (nn < N_) ? xb[(long)cc * N_ + nn] : 0.f;
  }
  __syncthreads();
#pragma unroll
  for (int i = 0; i < 4; ++i) {
    const int nn = n0 + ty + i * 8, cc = c0 + tx;
    xTb[(long)nn * C_ + cc] = f2h(t[tx][ty + i * 8]);
  }
}

__global__ __launch_bounds__(256) void cvt_f16(
    const float* __restrict__ src, uint16_t* __restrict__ dst, int n) {
  int i = blockIdx.x * 256 + threadIdx.x;
  const int stride = gridDim.x * 256;
  for (; i < n; i += stride) dst[i] = f2h(src[i]);
}

__global__ __launch_bounds__(256) void concat_bias(
    const float* __restrict__ a, const float* __restrict__ b,
    float* __restrict__ d) {
  const int i = blockIdx.x * 256 + threadIdx.x;
  if (i < 512) d[i] = a[i];
  else if (i < 1024) d[i] = b[i - 512];
}

// ---------------------------------------------------------------------------
// in-place row softmax on fp16 f [*, NP, NP]; cols >= N_ zeroed, rows >= N_
// zeroed entirely. blockIdx.x = row, blockIdx.y = batch-in-group.
// ---------------------------------------------------------------------------
__global__ __launch_bounds__(256) void softmax_inplace(uint16_t* __restrict__ f) {
  const int row = blockIdx.x, tid = threadIdx.x;
  uint16_t* p = f + ((long)blockIdx.y * NP + row) * NP;
  if (row >= N_) {
    for (int i = tid; i < NP; i += 256) p[i] = 0;
    return;
  }
  __shared__ float buf[N_];
  __shared__ float red[8];
  float mx = -3.4e38f;
  for (int ch = tid; ch < N_ / 8; ch += 256) {
    const f16x8 v = *reinterpret_cast<const f16x8*>(p + ch * 8);
#pragma unroll
    for (int j = 0; j < 8; ++j) {
      const float fv = (float)v[j];
      buf[ch * 8 + j] = fv;
      mx = fmaxf(mx, fv);
    }
  }
  for (int o = 32; o; o >>= 1) mx = fmaxf(mx, __shfl_xor(mx, o));
  if ((tid & 63) == 0) red[tid >> 6] = mx;
  __syncthreads();
  mx = fmaxf(fmaxf(red[0], red[1]), fmaxf(red[2], red[3]));

  float s = 0.f;
  for (int i = tid; i < N_; i += 256) {
    const float e = __expf(buf[i] - mx);
    buf[i] = e;
    s += e;
  }
  for (int o = 32; o; o >>= 1) s += __shfl_xor(s, o);
  __syncthreads();
  if ((tid & 63) == 0) red[tid >> 6] = s;
  __syncthreads();
  const float rinv = 1.0f / (red[0] + red[1] + red[2] + red[3]);

  for (int ch = tid; ch < N_ / 8; ch += 256) {
    f16x8 o8;
#pragma unroll
    for (int j = 0; j < 8; ++j) o8[j] = (_Float16)(buf[ch * 8 + j] * rinv);
    *reinterpret_cast<f16x8*>(p + ch * 8) = o8;
  }
  for (int i = N_ + tid; i < NP; i += 256) p[i] = 0;
}

// ---------------------------------------------------------------------------
// BN stats over fp16 z [B][C][NP] (cols < N_ only).
// ---------------------------------------------------------------------------
__global__ __launch_bounds__(256) void bn_stats(
    const _Float16* __restrict__ z, const float* __restrict__ gamma,
    const float* __restrict__ beta, float* __restrict__ ss) {
  const int c = blockIdx.x, tid = threadIdx.x;
  float sum = 0.f, sq = 0.f;
  for (int b = 0; b < B_; ++b) {
    const _Float16* zp = z + ((long)b * C_ + c) * NP;
    for (int ch = tid; ch < N_ / 8; ch += 256) {
      const f16x8 v = *(const f16x8*)(zp + ch * 8);
#pragma unroll
      for (int j = 0; j < 8; ++j) {
        const float fv = (float)v[j];
        sum += fv;
        sq += fv * fv;
      }
    }
  }
  for (int o = 32; o; o >>= 1) {
    sum += __shfl_xor(sum, o);
    sq += __shfl_xor(sq, o);
  }
  __shared__ float r1[8], r2[8];
  if ((tid & 63) == 0) { r1[tid >> 6] = sum; r2[tid >> 6] = sq; }
  __syncthreads();
  if (tid == 0) {
    sum = r1[0] + r1[1] + r1[2] + r1[3];
    sq  = r2[0] + r2[1] + r2[2] + r2[3];
    const float inv_n = 1.0f / (float)(B_ * N_);
    const float mean = sum * inv_n;
    const float var = sq * inv_n - mean * mean;
    const float sc = gamma[c] * rsqrtf(var + BN_EPS);
    ss[c] = sc;
    ss[C_ + c] = beta[c] - mean * sc;
  }
}

__global__ __launch_bounds__(256) void bn_apply(
    const _Float16* __restrict__ z, const float* __restrict__ x,
    const float* __restrict__ ss, float* __restrict__ out) {
  constexpr int CH = N_ / 8;  // 392 8-element chunks per row
  const long nv = (long)B_ * C_ * CH;
  const long stride = (long)gridDim.x * 256;
  for (long v = (long)blockIdx.x * 256 + threadIdx.x; v < nv; v += stride) {
    const long row = v / CH;
    const int ch = (int)(v % CH);
    const int c = (int)(row % C_);
    const f16x8 zz = *(const f16x8*)(z + row * NP + ch * 8);
    const float4 x0 = *(const float4*)(x + row * (long)N_ + ch * 8);
    const float4 x1 = *(const float4*)(x + row * (long)N_ + ch * 8 + 4);
    const float sc = ss[c], sh = ss[C_ + c];
    float4 o0, o1;
    o0.x = (float)zz[0] * sc + sh + x0.x;
    o0.y = (float)zz[1] * sc + sh + x0.y;
    o0.z = (float)zz[2] * sc + sh + x0.z;
    o0.w = (float)zz[3] * sc + sh + x0.w;
    o1.x = (float)zz[4] * sc + sh + x1.x;
    o1.y = (float)zz[5] * sc + sh + x1.y;
    o1.z = (float)zz[6] * sc + sh + x1.z;
    o1.w = (float)zz[7] * sc + sh + x1.w;
    *(float4*)(out + row * (long)N_ + ch * 8) = o0;
    *(float4*)(out + row * (long)N_ + ch * 8 + 4) = o1;
  }
}

// ---------------------------------------------------------------------------
extern "C" void kernel_launch(void* const* d_in, const int* in_sizes, int n_in,
                              void* d_out, int out_size, void* d_ws,
                              size_t ws_size, hipStream_t stream) {
  const float* x       = (const float*)d_in[0];
  const float* theta_w = (const float*)d_in[1];
  const float* theta_b = (const float*)d_in[2];
  const float* phi_w   = (const float*)d_in[3];
  const float* phi_b   = (const float*)d_in[4];
  const float* g_w     = (const float*)d_in[5];
  const float* g_b     = (const float*)d_in[6];
  const float* wz_w    = (const float*)d_in[7];
  const float* wz_b    = (const float*)d_in[8];
  const float* gamma   = (const float*)d_in[9];
  const float* beta    = (const float*)d_in[10];
  float* out = (float*)d_out;

  char* ws = (char*)d_ws;
  size_t off = 0;
  auto alloc = [&](size_t bytes) {
    void* p = ws + off;
    off += (bytes + 255) & ~(size_t)255;
    return p;
  };
  uint16_t* wfused = (uint16_t*)alloc((size_t)1024 * 1024 * 2);  // theta|phi
  uint16_t* wg     = (uint16_t*)alloc((size_t)CI_ * C_ * 2);
  uint16_t* wzh    = (uint16_t*)alloc((size_t)C_ * CI_ * 2);
  float*    bfused = (float*)alloc((size_t)1024 * 4);
  uint16_t* projT  = (uint16_t*)alloc((size_t)B_ * NP * 1024 * 2);  // theta|phi cols
  uint16_t* gbuf   = (uint16_t*)alloc((size_t)B_ * CI_ * NP * 2);
  uint16_t* ybuf   = (uint16_t*)alloc((size_t)B_ * NP * CI_ * 2);
  uint16_t* zbuf   = (uint16_t*)alloc((size_t)B_ * C_ * NP * 2);
  float*    ss     = (float*)alloc((size_t)C_ * 2 * 4);

  // xT and fattn share one region (xT dead once g-GEMM has run).
  const size_t xTb = (size_t)B_ * NP * C_ * 2;
  const size_t attnB = (size_t)NP * NP * 2;
  int G = 8;
  while (G > 1 && off + ((xTb > (size_t)G * attnB ? xTb : (size_t)G * attnB) + 255) > ws_size)
    G >>= 1;
  const size_t regionB = xTb > (size_t)G * attnB ? xTb : (size_t)G * attnB;
  uint16_t* xT    = (uint16_t*)alloc(regionB);
  uint16_t* fattn = xT;
  if (off > ws_size) {
    fprintf(stderr, "kernel_launch: workspace too small: need %zu have %zu\n",
            off, ws_size);
    return;
  }

  // weights -> fp16
  cvt_f16<<<512, 256, 0, stream>>>(theta_w, wfused, CI_ * C_);
  cvt_f16<<<512, 256, 0, stream>>>(phi_w, wfused + 512 * 1024, CI_ * C_);
  cvt_f16<<<512, 256, 0, stream>>>(g_w, wg, CI_ * C_);
  cvt_f16<<<512, 256, 0, stream>>>(wz_w, wzh, C_ * CI_);
  concat_bias<<<4, 256, 0, stream>>>(theta_b, phi_b, bfused);

  // x -> xT fp16 [B, NP, C]
  transpose_cast<<<dim3(NP / 32, C_ / 32, B_), 256, 0, stream>>>(x, xT);

  // projT[b*NP+n, o] = sum_k xT*wfused + bfused[o]   (o<512: theta, >=512: phi)
  gemm256<2><<<dim3(B_ * NP / 256 * 4), 512, 0, stream>>>(
      xT, wfused, projT, bfused, C_, C_, C_, 1024,
      0, 0, 0, B_ * NP / 256, 4);
  // gbuf[b][ci][n] = sum_k wg[ci,k]*xT[b,n,k] + g_b[ci]
  gemm256<1><<<dim3(2 * 13 * B_), 512, 0, stream>>>(
      wg, xT, gbuf, g_b, C_, C_, C_, NP,
      0, (long)NP * C_, (long)CI_ * NP, 2, 13);

  for (int g0 = 0; g0 < B_; g0 += G) {
    // f[n,m] = theta_n . phi_m   (fp16, in-place softmax next)
    gemm256<0><<<dim3(13 * 13 * G), 512, 0, stream>>>(
        projT + (size_t)g0 * NP * 1024, projT + (size_t)g0 * NP * 1024 + 512,
        fattn, nullptr, CI_, 1024, 1024, NP,
        (long)NP * 1024, (long)NP * 1024, (long)NP * NP, 13, 13);
    softmax_inplace<<<dim3(NP, G), 256, 0, stream>>>(fattn);
    // y[n,ci] = sum_m attn[n,m]*gbuf[ci,m]
    gemm256<0><<<dim3(13 * 2 * G), 512, 0, stream>>>(
        fattn, gbuf + (size_t)g0 * CI_ * NP, ybuf + (size_t)g0 * NP * CI_,
        nullptr, NP, NP, NP, CI_,
        (long)NP * NP, (long)CI_ * NP, (long)NP * CI_, 13, 2);
  }
  // z[c,n] = sum_ci wz[c,ci]*y[n,ci] + wz_b[c]   (all 8 batches)
  gemm256<1><<<dim3(4 * 13 * B_), 512, 0, stream>>>(
      wzh, ybuf, zbuf, wz_b, CI_, CI_, CI_, NP,
      0, (long)NP * CI_, (long)C_ * NP, 4, 13);

  bn_stats<<<C_, 256, 0, stream>>>((const _Float16*)zbuf, gamma, beta, ss);
  bn_apply<<<4096, 256, 0, stream>>>((const _Float16*)zbuf, x, ss, out);
}

// Round 5
// 513.165 us; speedup vs baseline: 2.7369x; 1.0337x over previous
//
#include <hip/hip_runtime.h>
#include <cstdint>
#include <cstdio>

#define DEVINL __device__ __forceinline__

typedef _Float16 f16x8 __attribute__((ext_vector_type(8)));
typedef float    f32x4 __attribute__((ext_vector_type(4)));

static constexpr int B_  = 8;
static constexpr int C_  = 1024;
static constexpr int CI_ = 512;
static constexpr int N_  = 56 * 56;   // 3136
static constexpr int NP  = 3328;      // padded to multiple of 256
static constexpr float BN_EPS = 1e-5f;

DEVINL uint16_t f2h(float f) {
  union { _Float16 h; uint16_t u; } cv;
  cv.h = (_Float16)f;   // RNE
  return cv.u;
}

DEVINL void async16(const void* g, void* lds) {
  __builtin_amdgcn_global_load_lds(
      (const __attribute__((address_space(1))) uint32_t*)g,
      (__attribute__((address_space(3))) uint32_t*)lds, 16, 0, 0);
}

// ---------------------------------------------------------------------------
// 256x256 8-phase TN GEMM (m201 template, fp16 in / fp16 out, fp32 acc).
// C[m,n] = sum_k A[m,k]*Bt[n,k] (+bias). M%256==0, N%256==0, K%128==0.
// 512 threads = 8 waves (2M x 4N); per-wave output 128x64; acc[8][4] f32x4.
// LDS 128KB: A/B x 2 bufs x 2 k-slices(32) of [256][32] fp16 (16KB half-tiles).
// Swizzle: 16B chunk within row: phys = c ^ ((row>>1)&3). Rows alternate 64B
// bank-halves via row&1; (row>>1)&3 cycles the 4 chunk slots across the 8
// same-parity rows -> 2 lanes/slot on ds_read_b128 (2-way = free, m136).
// Both-sides rule (m104): staged global source pre-swizzled, LDS stays linear,
// read applies same XOR. Counted vmcnt(8) only, twice per K-tile; per-phase
// barrier + lgkmcnt(0) + sched_barrier(0).  BIAS: 0 none, 1 per-row, 2 per-col.
// ---------------------------------------------------------------------------
template <int BIAS>
__global__ __launch_bounds__(512, 2) void gemm256(
    const uint16_t* __restrict__ A, const uint16_t* __restrict__ Bt,
    uint16_t* __restrict__ Cc, const float* __restrict__ bias,
    int K, int lda, int ldb, int ldc,
    long aBatch, long bBatch, long cBatch, int nbx, int nby) {
  __shared__ uint16_t lds[65536];   // 128 KiB

  // bijective XCD swizzle (m204)
  const int nwg = gridDim.x, orig = blockIdx.x;
  const int q = nwg >> 3, r = nwg & 7, xcd = orig & 7, idx = orig >> 3;
  const int wgid = (xcd < r ? xcd * (q + 1) : r * (q + 1) + (xcd - r) * q) + idx;
  const int bx = wgid % nbx;
  const int by = (wgid / nbx) % nby;
  const int zb = wgid / (nbx * nby);

  const int tid = threadIdx.x, w = tid >> 6, l = tid & 63;
  const int wm = w >> 2, wn = w & 3, lr = l & 15, lg = l >> 4;

  const uint16_t* Ab = A + (long)zb * aBatch + (long)bx * 256 * lda;
  const uint16_t* Bb = Bt + (long)zb * bBatch + (long)by * 256 * ldb;

  const int NT = K >> 6;

  // staging: half-tile = [256 rows][32 k] fp16 = 1024 chunks of 16B, 2 instrs.
  // chunk c: row=c>>2, source col pre-swizzled with swz(row)=(row>>1)&3 =
  // (c>>3)&3:  col16 = (c&3) ^ ((c>>3)&3)
  const int c0 = tid, c1 = 512 + tid;
  const long aoff0 = (long)(c0 >> 2) * lda + (((c0 & 3) ^ ((c0 >> 3) & 3)) * 8);
  const long aoff1 = (long)(c1 >> 2) * lda + (((c1 & 3) ^ ((c1 >> 3) & 3)) * 8);
  const long boff0 = (long)(c0 >> 2) * ldb + (((c0 & 3) ^ ((c0 >> 3) & 3)) * 8);
  const long boff1 = (long)(c1 >> 2) * ldb + (((c1 & 3) ^ ((c1 >> 3) & 3)) * 8);
  const int ldsW0 = (w * 64) * 8;          // wave-uniform dest (elems), instr 0
  const int ldsW1 = (512 + w * 64) * 8;    // instr 1

  auto stageA = [&](int t, int ks, int buf) {
    const int tw = t >= NT ? t - NT : t;   // wrap: garbage lands in dead region
    const uint16_t* src = Ab + tw * 64 + ks * 32;
    const int reg = (buf * 2 + ks) * 8192;
    async16(src + aoff0, &lds[reg + ldsW0]);
    async16(src + aoff1, &lds[reg + ldsW1]);
  };
  auto stageB = [&](int t, int ks, int buf) {
    const int tw = t >= NT ? t - NT : t;
    const uint16_t* src = Bb + tw * 64 + ks * 32;
    const int reg = 32768 + (buf * 2 + ks) * 8192;
    async16(src + boff0, &lds[reg + ldsW0]);
    async16(src + boff1, &lds[reg + ldsW1]);
  };

  // read-side swizzle: row = 16*base + lr -> (row>>1)&3 == (lr>>1)&3
  const int laneSwz = (lg ^ ((lr >> 1) & 3)) * 8;
  f32x4 acc[8][4] = {};
  f16x8 af[4], bf[4];

#define LOAD_A(b, ks, mh)                                                     \
  _Pragma("unroll") for (int i = 0; i < 4; ++i) {                             \
    const int row_ = wm * 128 + ((mh) * 4 + i) * 16 + lr;                     \
    af[i] = *reinterpret_cast<const f16x8*>(                                  \
        &lds[((b) * 2 + (ks)) * 8192 + row_ * 32 + laneSwz]);                 \
  }
#define LOAD_B(b, ks)                                                         \
  _Pragma("unroll") for (int i = 0; i < 4; ++i) {                             \
    const int row_ = wn * 64 + i * 16 + lr;                                   \
    bf[i] = *reinterpret_cast<const f16x8*>(                                  \
        &lds[32768 + ((b) * 2 + (ks)) * 8192 + row_ * 32 + laneSwz]);         \
  }
#define MFMA16(mh)                                                            \
  _Pragma("unroll") for (int i = 0; i < 4; ++i)                               \
  _Pragma("unroll") for (int j = 0; j < 4; ++j)                               \
    acc[(mh) * 4 + i][j] = __builtin_amdgcn_mfma_f32_16x16x32_f16(            \
        af[i], bf[j], acc[(mh) * 4 + i][j], 0, 0, 0);
#define WAIT_LGKM()                                       \
  asm volatile("s_waitcnt lgkmcnt(0)" ::: "memory");      \
  __builtin_amdgcn_sched_barrier(0);
#define WAIT_VM8()                                        \
  asm volatile("s_waitcnt vmcnt(8)" ::: "memory");        \
  __builtin_amdgcn_sched_barrier(0);

#define TILE(t, b)                                                            \
  {                                                                           \
    /* P1: k-slice0, m-half0 */                                               \
    LOAD_B(b, 0); LOAD_A(b, 0, 0);                                            \
    stageA((t) + 1, 1, (b) ^ 1);                                              \
    __builtin_amdgcn_s_barrier(); WAIT_LGKM();                                \
    __builtin_amdgcn_s_setprio(1); MFMA16(0); __builtin_amdgcn_s_setprio(0);  \
    __builtin_amdgcn_s_barrier();                                             \
    /* P2: k-slice0, m-half1 */                                               \
    LOAD_A(b, 0, 1);                                                          \
    stageB((t) + 1, 1, (b) ^ 1);                                              \
    __builtin_amdgcn_s_barrier(); WAIT_LGKM();                                \
    __builtin_amdgcn_s_setprio(1); MFMA16(1); __builtin_amdgcn_s_setprio(0);  \
    WAIT_VM8();                                                               \
    __builtin_amdgcn_s_barrier();                                             \
    /* P3: k-slice1, m-half0 */                                               \
    LOAD_B(b, 1); LOAD_A(b, 1, 0);                                            \
    stageA((t) + 2, 0, (b));                                                  \
    __builtin_amdgcn_s_barrier(); WAIT_LGKM();                                \
    __builtin_amdgcn_s_setprio(1); MFMA16(0); __builtin_amdgcn_s_setprio(0);  \
    __builtin_amdgcn_s_barrier();                                             \
    /* P4: k-slice1, m-half1 */                                               \
    LOAD_A(b, 1, 1);                                                          \
    stageB((t) + 2, 0, (b));                                                  \
    __builtin_amdgcn_s_barrier(); WAIT_LGKM();                                \
    __builtin_amdgcn_s_setprio(1); MFMA16(1); __builtin_amdgcn_s_setprio(0);  \
    WAIT_VM8();                                                               \
    __builtin_amdgcn_s_barrier();                                             \
  }

  // prologue: tile0 (all 4 halves) + tile1 k-slice0 = 6 stages (12 loads);
  // vmcnt(8) -> oldest 4 loads (A/B k0 of tile0) landed.
  stageA(0, 0, 0); stageB(0, 0, 0);
  stageA(0, 1, 0); stageB(0, 1, 0);
  stageA(1, 0, 1); stageB(1, 0, 1);
  WAIT_VM8();
  __builtin_amdgcn_s_barrier();

  for (int tp = 0; tp < NT; tp += 2) {   // K%128==0 -> NT even
    TILE(tp, 0);
    TILE(tp + 1, 1);
  }

#undef TILE
#undef LOAD_A
#undef LOAD_B
#undef MFMA16
#undef WAIT_LGKM
#undef WAIT_VM8

  uint16_t* Cp = Cc + (long)zb * cBatch + ((long)bx * 256) * ldc + (long)by * 256;
#pragma unroll
  for (int mf = 0; mf < 8; ++mf) {
#pragma unroll
    for (int nf = 0; nf < 4; ++nf) {
      const int col = wn * 64 + nf * 16 + lr;
      const f32x4 v = acc[mf][nf];
#pragma unroll
      for (int qq = 0; qq < 4; ++qq) {
        const int row = wm * 128 + mf * 16 + lg * 4 + qq;
        float val = v[qq];
        if constexpr (BIAS == 1) val += bias[bx * 256 + row];
        if constexpr (BIAS == 2) val += bias[by * 256 + col];
        Cp[(long)row * ldc + col] = f2h(val);
      }
    }
  }
}

// ---------------------------------------------------------------------------
// x [C,N] fp32 -> xT [NP,C] fp16 (zero-padded rows n >= N_)
// ---------------------------------------------------------------------------
__global__ __launch_bounds__(256) void transpose_cast(
    const float* __restrict__ x, uint16_t* __restrict__ xT) {
  __shared__ float t[32][33];
  const int b = blockIdx.z;
  const float* xb = x + (long)b * C_ * N_;
  uint16_t* xTb = xT + (long)b * NP * C_;
  const int n0 = blockIdx.x * 32, c0 = blockIdx.y * 32;
  const int tx = threadIdx.x & 31, ty = threadIdx.x >> 5;
#pragma unroll
  for (int i = 0; i < 4; ++i) {
    const int cc = c0 + ty + i * 8, nn = n0 + tx;
    t[ty + i * 8][tx] = (nn < N_) ? xb[(long)cc * N_ + nn] : 0.f;
  }
  __syncthreads();
#pragma unroll
  for (int i = 0; i < 4; ++i) {
    const int nn = n0 + ty + i * 8, cc = c0 + tx;
    xTb[(long)nn * C_ + cc] = f2h(t[tx][ty + i * 8]);
  }
}

__global__ __launch_bounds__(256) void cvt_f16(
    const float* __restrict__ src, uint16_t* __restrict__ dst, int n) {
  int i = blockIdx.x * 256 + threadIdx.x;
  const int stride = gridDim.x * 256;
  for (; i < n; i += stride) dst[i] = f2h(src[i]);
}

__global__ __launch_bounds__(256) void concat_bias(
    const float* __restrict__ a, const float* __restrict__ b,
    float* __restrict__ d) {
  const int i = blockIdx.x * 256 + threadIdx.x;
  if (i < 512) d[i] = a[i];
  else if (i < 1024) d[i] = b[i - 512];
}

// ---------------------------------------------------------------------------
// in-place row softmax on fp16 f [*, NP, NP]; cols >= N_ zeroed, rows >= N_
// zeroed entirely. blockIdx.x = row, blockIdx.y = batch-in-group.
// ---------------------------------------------------------------------------
__global__ __launch_bounds__(256) void softmax_inplace(uint16_t* __restrict__ f) {
  const int row = blockIdx.x, tid = threadIdx.x;
  uint16_t* p = f + ((long)blockIdx.y * NP + row) * NP;
  if (row >= N_) {
    for (int i = tid; i < NP; i += 256) p[i] = 0;
    return;
  }
  __shared__ float buf[N_];
  __shared__ float red[8];
  float mx = -3.4e38f;
  for (int ch = tid; ch < N_ / 8; ch += 256) {
    const f16x8 v = *reinterpret_cast<const f16x8*>(p + ch * 8);
#pragma unroll
    for (int j = 0; j < 8; ++j) {
      const float fv = (float)v[j];
      buf[ch * 8 + j] = fv;
      mx = fmaxf(mx, fv);
    }
  }
  for (int o = 32; o; o >>= 1) mx = fmaxf(mx, __shfl_xor(mx, o));
  if ((tid & 63) == 0) red[tid >> 6] = mx;
  __syncthreads();
  mx = fmaxf(fmaxf(red[0], red[1]), fmaxf(red[2], red[3]));

  float s = 0.f;
  for (int i = tid; i < N_; i += 256) {
    const float e = __expf(buf[i] - mx);
    buf[i] = e;
    s += e;
  }
  for (int o = 32; o; o >>= 1) s += __shfl_xor(s, o);
  __syncthreads();
  if ((tid & 63) == 0) red[tid >> 6] = s;
  __syncthreads();
  const float rinv = 1.0f / (red[0] + red[1] + red[2] + red[3]);

  for (int ch = tid; ch < N_ / 8; ch += 256) {
    f16x8 o8;
#pragma unroll
    for (int j = 0; j < 8; ++j) o8[j] = (_Float16)(buf[ch * 8 + j] * rinv);
    *reinterpret_cast<f16x8*>(p + ch * 8) = o8;
  }
  for (int i = N_ + tid; i < NP; i += 256) p[i] = 0;
}

// ---------------------------------------------------------------------------
// BN stats over fp16 z [B][C][NP] (cols < N_ only).
// ---------------------------------------------------------------------------
__global__ __launch_bounds__(256) void bn_stats(
    const _Float16* __restrict__ z, const float* __restrict__ gamma,
    const float* __restrict__ beta, float* __restrict__ ss) {
  const int c = blockIdx.x, tid = threadIdx.x;
  float sum = 0.f, sq = 0.f;
  for (int b = 0; b < B_; ++b) {
    const _Float16* zp = z + ((long)b * C_ + c) * NP;
    for (int ch = tid; ch < N_ / 8; ch += 256) {
      const f16x8 v = *(const f16x8*)(zp + ch * 8);
#pragma unroll
      for (int j = 0; j < 8; ++j) {
        const float fv = (float)v[j];
        sum += fv;
        sq += fv * fv;
      }
    }
  }
  for (int o = 32; o; o >>= 1) {
    sum += __shfl_xor(sum, o);
    sq += __shfl_xor(sq, o);
  }
  __shared__ float r1[8], r2[8];
  if ((tid & 63) == 0) { r1[tid >> 6] = sum; r2[tid >> 6] = sq; }
  __syncthreads();
  if (tid == 0) {
    sum = r1[0] + r1[1] + r1[2] + r1[3];
    sq  = r2[0] + r2[1] + r2[2] + r2[3];
    const float inv_n = 1.0f / (float)(B_ * N_);
    const float mean = sum * inv_n;
    const float var = sq * inv_n - mean * mean;
    const float sc = gamma[c] * rsqrtf(var + BN_EPS);
    ss[c] = sc;
    ss[C_ + c] = beta[c] - mean * sc;
  }
}

__global__ __launch_bounds__(256) void bn_apply(
    const _Float16* __restrict__ z, const float* __restrict__ x,
    const float* __restrict__ ss, float* __restrict__ out) {
  constexpr int CH = N_ / 8;  // 392 8-element chunks per row
  const long nv = (long)B_ * C_ * CH;
  const long stride = (long)gridDim.x * 256;
  for (long v = (long)blockIdx.x * 256 + threadIdx.x; v < nv; v += stride) {
    const long row = v / CH;
    const int ch = (int)(v % CH);
    const int c = (int)(row % C_);
    const f16x8 zz = *(const f16x8*)(z + row * NP + ch * 8);
    const float4 x0 = *(const float4*)(x + row * (long)N_ + ch * 8);
    const float4 x1 = *(const float4*)(x + row * (long)N_ + ch * 8 + 4);
    const float sc = ss[c], sh = ss[C_ + c];
    float4 o0, o1;
    o0.x = (float)zz[0] * sc + sh + x0.x;
    o0.y = (float)zz[1] * sc + sh + x0.y;
    o0.z = (float)zz[2] * sc + sh + x0.z;
    o0.w = (float)zz[3] * sc + sh + x0.w;
    o1.x = (float)zz[4] * sc + sh + x1.x;
    o1.y = (float)zz[5] * sc + sh + x1.y;
    o1.z = (float)zz[6] * sc + sh + x1.z;
    o1.w = (float)zz[7] * sc + sh + x1.w;
    *(float4*)(out + row * (long)N_ + ch * 8) = o0;
    *(float4*)(out + row * (long)N_ + ch * 8 + 4) = o1;
  }
}

// ---------------------------------------------------------------------------
extern "C" void kernel_launch(void* const* d_in, const int* in_sizes, int n_in,
                              void* d_out, int out_size, void* d_ws,
                              size_t ws_size, hipStream_t stream) {
  const float* x       = (const float*)d_in[0];
  const float* theta_w = (const float*)d_in[1];
  const float* theta_b = (const float*)d_in[2];
  const float* phi_w   = (const float*)d_in[3];
  const float* phi_b   = (const float*)d_in[4];
  const float* g_w     = (const float*)d_in[5];
  const float* g_b     = (const float*)d_in[6];
  const float* wz_w    = (const float*)d_in[7];
  const float* wz_b    = (const float*)d_in[8];
  const float* gamma   = (const float*)d_in[9];
  const float* beta    = (const float*)d_in[10];
  float* out = (float*)d_out;

  char* ws = (char*)d_ws;
  size_t off = 0;
  auto alloc = [&](size_t bytes) {
    void* p = ws + off;
    off += (bytes + 255) & ~(size_t)255;
    return p;
  };
  uint16_t* wfused = (uint16_t*)alloc((size_t)1024 * 1024 * 2);  // theta|phi
  uint16_t* wg     = (uint16_t*)alloc((size_t)CI_ * C_ * 2);
  uint16_t* wzh    = (uint16_t*)alloc((size_t)C_ * CI_ * 2);
  float*    bfused = (float*)alloc((size_t)1024 * 4);
  uint16_t* projT  = (uint16_t*)alloc((size_t)B_ * NP * 1024 * 2);  // theta|phi cols
  uint16_t* gbuf   = (uint16_t*)alloc((size_t)B_ * CI_ * NP * 2);
  uint16_t* ybuf   = (uint16_t*)alloc((size_t)B_ * NP * CI_ * 2);
  uint16_t* zbuf   = (uint16_t*)alloc((size_t)B_ * C_ * NP * 2);
  float*    ss     = (float*)alloc((size_t)C_ * 2 * 4);

  // xT and fattn share one region (xT dead once g-GEMM has run).
  const size_t xTb = (size_t)B_ * NP * C_ * 2;
  const size_t attnB = (size_t)NP * NP * 2;
  int G = 8;
  while (G > 1 && off + ((xTb > (size_t)G * attnB ? xTb : (size_t)G * attnB) + 255) > ws_size)
    G >>= 1;
  const size_t regionB = xTb > (size_t)G * attnB ? xTb : (size_t)G * attnB;
  uint16_t* xT    = (uint16_t*)alloc(regionB);
  uint16_t* fattn = xT;
  if (off > ws_size) {
    fprintf(stderr, "kernel_launch: workspace too small: need %zu have %zu\n",
            off, ws_size);
    return;
  }

  // weights -> fp16
  cvt_f16<<<512, 256, 0, stream>>>(theta_w, wfused, CI_ * C_);
  cvt_f16<<<512, 256, 0, stream>>>(phi_w, wfused + 512 * 1024, CI_ * C_);
  cvt_f16<<<512, 256, 0, stream>>>(g_w, wg, CI_ * C_);
  cvt_f16<<<512, 256, 0, stream>>>(wz_w, wzh, C_ * CI_);
  concat_bias<<<4, 256, 0, stream>>>(theta_b, phi_b, bfused);

  // x -> xT fp16 [B, NP, C]
  transpose_cast<<<dim3(NP / 32, C_ / 32, B_), 256, 0, stream>>>(x, xT);

  // projT[b*NP+n, o] = sum_k xT*wfused + bfused[o]   (o<512: theta, >=512: phi)
  gemm256<2><<<dim3(B_ * NP / 256 * 4), 512, 0, stream>>>(
      xT, wfused, projT, bfused, C_, C_, C_, 1024,
      0, 0, 0, B_ * NP / 256, 4);
  // gbuf[b][ci][n] = sum_k wg[ci,k]*xT[b,n,k] + g_b[ci]
  gemm256<1><<<dim3(2 * 13 * B_), 512, 0, stream>>>(
      wg, xT, gbuf, g_b, C_, C_, C_, NP,
      0, (long)NP * C_, (long)CI_ * NP, 2, 13);

  for (int g0 = 0; g0 < B_; g0 += G) {
    // f[n,m] = theta_n . phi_m   (fp16, in-place softmax next)
    gemm256<0><<<dim3(13 * 13 * G), 512, 0, stream>>>(
        projT + (size_t)g0 * NP * 1024, projT + (size_t)g0 * NP * 1024 + 512,
        fattn, nullptr, CI_, 1024, 1024, NP,
        (long)NP * 1024, (long)NP * 1024, (long)NP * NP, 13, 13);
    softmax_inplace<<<dim3(NP, G), 256, 0, stream>>>(fattn);
    // y[n,ci] = sum_m attn[n,m]*gbuf[ci,m]
    gemm256<0><<<dim3(13 * 2 * G), 512, 0, stream>>>(
        fattn, gbuf + (size_t)g0 * CI_ * NP, ybuf + (size_t)g0 * NP * CI_,
        nullptr, NP, NP, NP, CI_,
        (long)NP * NP, (long)CI_ * NP, (long)NP * CI_, 13, 2);
  }
  // z[c,n] = sum_ci wz[c,ci]*y[n,ci] + wz_b[c]   (all 8 batches)
  gemm256<1><<<dim3(4 * 13 * B_), 512, 0, stream>>>(
      wzh, ybuf, zbuf, wz_b, CI_, CI_, CI_, NP,
      0, (long)NP * CI_, (long)C_ * NP, 4, 13);

  bn_stats<<<C_, 256, 0, stream>>>((const _Float16*)zbuf, gamma, beta, ss);
  bn_apply<<<4096, 256, 0, stream>>>((const _Float16*)zbuf, x, ss, out);
}